// Round 1
// baseline (482.234 us; speedup 1.0000x reference)
//
#include <hip/hip_runtime.h>
#include <hip/hip_bf16.h>

// Factorized (Kronecker) linear: out[b,i,j,k] = sum_{p,q,r} x[b,p,q,r] W1[p,i] W2[q,j] W3[r,k]
// One block per batch row; all three K=32 contractions fused, intermediates in LDS (bf16).
//
// LDS layout: A(a0,a1,a2) = a0*1024 + a1*32 + ((a2 + a1) & 31)   (bf16, 64 KB exactly)
// The (+a1) rotation makes the stride-1 stage-3 column reads hit all 32 banks.
// Each stage's thread owns a column whose read-set == write-set -> in-place, 2 barriers total.

#define FD 32
#define NROW 32768  // 32*32*32 features per row

__global__ __launch_bounds__(1024, 8) void kron3_fused(
    const float* __restrict__ x,
    const float* __restrict__ W1,
    const float* __restrict__ W2,
    const float* __restrict__ W3,
    float* __restrict__ out)
{
    __shared__ __hip_bfloat16 buf[NROW];  // 65536 bytes

    const int b = blockIdx.x;
    const int t = threadIdx.x;
    const float* __restrict__ xrow = x + (size_t)b * NROW;

    // ---------------- Stage 1: contract p  (y[i,q,r] = sum_p x[p,q,r] W1[p,i]) ----------------
    // thread -> (q,r). Global reads: lanes cover 256 contiguous bytes per load -> coalesced.
    {
        const int q = t >> 5;
        const int r = t & 31;
        float acc[FD];
#pragma unroll
        for (int i = 0; i < FD; ++i) acc[i] = 0.0f;
#pragma unroll
        for (int p = 0; p < FD; ++p) {
            const float xv = xrow[p * 1024 + q * 32 + r];
#pragma unroll
            for (int i = 0; i < FD; ++i) acc[i] += xv * W1[p * 32 + i];  // W1: uniform -> s_load
        }
        const int rowbase = q * 32;
#pragma unroll
        for (int i = 0; i < FD; ++i)
            buf[i * 1024 + rowbase + ((r + q) & 31)] = __float2bfloat16(acc[i]);
    }
    __syncthreads();

    // ---------------- Stage 2: contract q  (z[i,j,r] = sum_q y[i,q,r] W2[q,j]) ----------------
    // thread -> (i,r). Read set == write set (same (i,*,r) slots) -> in-place safe.
    {
        const int i = t >> 5;
        const int r = t & 31;
        float acc[FD];
#pragma unroll
        for (int j = 0; j < FD; ++j) acc[j] = 0.0f;
#pragma unroll
        for (int q = 0; q < FD; ++q) {
            const float xv = __bfloat162float(buf[i * 1024 + q * 32 + ((r + q) & 31)]);
#pragma unroll
            for (int j = 0; j < FD; ++j) acc[j] += xv * W2[q * 32 + j];
        }
#pragma unroll
        for (int j = 0; j < FD; ++j)
            buf[i * 1024 + j * 32 + ((r + j) & 31)] = __float2bfloat16(acc[j]);
    }
    __syncthreads();

    // ---------------- Stage 3: contract r  (out[i,j,k] = sum_r z[i,j,r] W3[r,k]) ---------------
    // thread -> (i,j). Output kk is contiguous in global -> float4 coalesced stores.
    {
        const int i = t >> 5;
        const int j = t & 31;
        float acc[FD];
#pragma unroll
        for (int k = 0; k < FD; ++k) acc[k] = 0.0f;
#pragma unroll
        for (int r = 0; r < FD; ++r) {
            const float xv = __bfloat162float(buf[i * 1024 + j * 32 + ((r + j) & 31)]);
#pragma unroll
            for (int k = 0; k < FD; ++k) acc[k] += xv * W3[r * 32 + k];
        }
        float* __restrict__ orow = out + (size_t)b * NROW + i * 1024 + j * 32;
        float4* __restrict__ dst = reinterpret_cast<float4*>(orow);
#pragma unroll
        for (int v = 0; v < 8; ++v)
            dst[v] = make_float4(acc[4 * v + 0], acc[4 * v + 1], acc[4 * v + 2], acc[4 * v + 3]);
    }
}

extern "C" void kernel_launch(void* const* d_in, const int* in_sizes, int n_in,
                              void* d_out, int out_size, void* d_ws, size_t ws_size,
                              hipStream_t stream) {
    const float* x  = (const float*)d_in[0];
    const float* W1 = (const float*)d_in[1];
    const float* W2 = (const float*)d_in[2];
    const float* W3 = (const float*)d_in[3];
    float* outp = (float*)d_out;

    const int batch = in_sizes[0] / NROW;  // 2048
    kron3_fused<<<dim3(batch), dim3(1024), 0, stream>>>(x, W1, W2, W3, outp);
}

// Round 2
// 200.414 us; speedup vs baseline: 2.4062x; 2.4062x over previous
//
#include <hip/hip_runtime.h>
#include <hip/hip_bf16.h>

// Factorized (Kronecker) linear: out[b,i,j,k] = sum_{p,q,r} x[b,p,q,r] W1[p,i] W2[q,j] W3[r,k]
// One block per batch row; all three K=32 contractions fused, intermediates in LDS (bf16).
//
// LDS layout: A(a0,a1,a2) = a0*1024 + a1*32 + ((a2 + a1) & 31)   (bf16, 64 KB exactly)
// The (+a1) rotation makes the stride-1 stage-3 column reads hit all 32 banks.
// Each stage's thread owns a column whose read-set == write-set -> in-place, 2 barriers total.
//
// R2 change vs R1: contraction loops are `#pragma unroll 4` instead of full 32-way.
// R1's 32x32=1024-stmt unrolled bodies made LLVM bail on full unroll, leaving acc[]
// runtime-indexed -> scratch (VGPR_Count=32, +330MB scratch WRITE_SIZE, 482us).
// 4x32=128-stmt bodies unroll cleanly -> acc[] stays in VGPRs (est. ~48 regs < 64 cap).

#define FD 32
#define NROW 32768  // 32*32*32 features per row

__global__ __launch_bounds__(1024, 8) void kron3_fused(
    const float* __restrict__ x,
    const float* __restrict__ W1,
    const float* __restrict__ W2,
    const float* __restrict__ W3,
    float* __restrict__ out)
{
    __shared__ __hip_bfloat16 buf[NROW];  // 65536 bytes

    const int b = blockIdx.x;
    const int t = threadIdx.x;
    const float* __restrict__ xrow = x + (size_t)b * NROW;

    // ---------------- Stage 1: contract p  (y[i,q,r] = sum_p x[p,q,r] W1[p,i]) ----------------
    // thread -> (q,r). Global reads: lanes cover 256 contiguous bytes per load -> coalesced.
    {
        const int q = t >> 5;
        const int r = t & 31;
        float acc[FD];
#pragma unroll
        for (int i = 0; i < FD; ++i) acc[i] = 0.0f;
#pragma unroll 4
        for (int p = 0; p < FD; ++p) {
            const float xv = xrow[p * 1024 + q * 32 + r];
#pragma unroll
            for (int i = 0; i < FD; ++i) acc[i] += xv * W1[p * 32 + i];  // W1: uniform -> s_load
        }
        const int rowbase = q * 32;
#pragma unroll
        for (int i = 0; i < FD; ++i)
            buf[i * 1024 + rowbase + ((r + q) & 31)] = __float2bfloat16(acc[i]);
    }
    __syncthreads();

    // ---------------- Stage 2: contract q  (z[i,j,r] = sum_q y[i,q,r] W2[q,j]) ----------------
    // thread -> (i,r). Read set == write set (same (i,*,r) slots) -> in-place safe.
    {
        const int i = t >> 5;
        const int r = t & 31;
        float acc[FD];
#pragma unroll
        for (int j = 0; j < FD; ++j) acc[j] = 0.0f;
#pragma unroll 4
        for (int q = 0; q < FD; ++q) {
            const float xv = __bfloat162float(buf[i * 1024 + q * 32 + ((r + q) & 31)]);
#pragma unroll
            for (int j = 0; j < FD; ++j) acc[j] += xv * W2[q * 32 + j];
        }
#pragma unroll
        for (int j = 0; j < FD; ++j)
            buf[i * 1024 + j * 32 + ((r + j) & 31)] = __float2bfloat16(acc[j]);
    }
    __syncthreads();

    // ---------------- Stage 3: contract r  (out[i,j,k] = sum_r z[i,j,r] W3[r,k]) ---------------
    // thread -> (i,j). Output kk is contiguous in global -> float4 coalesced stores.
    {
        const int i = t >> 5;
        const int j = t & 31;
        float acc[FD];
#pragma unroll
        for (int k = 0; k < FD; ++k) acc[k] = 0.0f;
#pragma unroll 4
        for (int r = 0; r < FD; ++r) {
            const float xv = __bfloat162float(buf[i * 1024 + j * 32 + ((r + j) & 31)]);
#pragma unroll
            for (int k = 0; k < FD; ++k) acc[k] += xv * W3[r * 32 + k];
        }
        float* __restrict__ orow = out + (size_t)b * NROW + i * 1024 + j * 32;
        float4* __restrict__ dst = reinterpret_cast<float4*>(orow);
#pragma unroll
        for (int v = 0; v < 8; ++v)
            dst[v] = make_float4(acc[4 * v + 0], acc[4 * v + 1], acc[4 * v + 2], acc[4 * v + 3]);
    }
}

extern "C" void kernel_launch(void* const* d_in, const int* in_sizes, int n_in,
                              void* d_out, int out_size, void* d_ws, size_t ws_size,
                              hipStream_t stream) {
    const float* x  = (const float*)d_in[0];
    const float* W1 = (const float*)d_in[1];
    const float* W2 = (const float*)d_in[2];
    const float* W3 = (const float*)d_in[3];
    float* outp = (float*)d_out;

    const int batch = in_sizes[0] / NROW;  // 2048
    kron3_fused<<<dim3(batch), dim3(1024), 0, stream>>>(x, W1, W2, W3, outp);
}

// Round 3
// 120.522 us; speedup vs baseline: 4.0012x; 1.6629x over previous
//
#include <hip/hip_runtime.h>
#include <hip/hip_bf16.h>

// out[b,i,j,k] = sum_{p,q,r} x[b,p,q,r] W1[p,i] W2[q,j] W3[r,k]
// Contractions commute -> do r (stage A), then q (B), then p (C), so every
// stage contracts the CURRENT fastest axis (contiguous-k MFMA frags) and each
// stage writes transposed so the next axis becomes fast:
//   x   : [mA=(p,q)][r]   (natural)        -> stage A contracts r
//   yA  : [mB=(p,k)][q]                    -> stage B contracts q
//   yB  : [mC=(j,k)][p]                    -> stage C contracts p
//   out : [i][j][k]  k fast -> float4 coalesced stores
// One 64KB bf16 LDS buffer, in-place, XOR bank swizzle on the 8-elem column
// blocks. MFMA 16x16x32 bf16: A/B lane l holds k=8*(l>>4)+j; C/D col=l&15,
// row=4*(l>>4)+reg (m89). Stage B uses swapped operands (W2 as A) so its
// scalar C-writes vary k per lane (8-way banks instead of 64-way).

typedef __attribute__((ext_vector_type(8))) short bf16x8;
typedef __attribute__((ext_vector_type(4))) float f32x4;

#define NROW 32768

__device__ __forceinline__ unsigned short f2b(float f) {
    union { float f; unsigned u; } v; v.f = f;
    unsigned r = v.u + 0x7fffu + ((v.u >> 16) & 1u);   // RNE bf16
    return (unsigned short)(r >> 16);
}

// swizzled element index: column XOR'd (8-granular) by row hash -> b128-safe
__device__ __forceinline__ int swz(int row, int col) {
    int s = ((row ^ (row >> 2) ^ (row >> 4)) & 3) << 3;
    return row * 32 + (col ^ s);
}

// weight fragment: lane (c,g) holds W[k=8g+j][n=16h+c], j=0..7 (k-consecutive)
__device__ __forceinline__ bf16x8 wfrag(const float* __restrict__ W, int h, int c, int g) {
    bf16x8 r;
#pragma unroll
    for (int j = 0; j < 8; ++j)
        r[j] = (short)f2b(W[(8 * g + j) * 32 + 16 * h + c]);
    return r;
}

// LDS fragment: lane (c-> row sel, g-> k block) reads 8 contiguous (swizzled) cols
__device__ __forceinline__ bf16x8 ldsfrag(const unsigned short* buf, int row, int g) {
    int s = (row ^ (row >> 2) ^ (row >> 4)) & 3;
    union { uint4 u; bf16x8 b; } cv;
    cv.u = *(const uint4*)(buf + row * 32 + 8 * (g ^ s));
    return cv.b;
}

__global__ __launch_bounds__(1024, 8) void kron3_mfma(
    const float* __restrict__ x,  const float* __restrict__ W1,
    const float* __restrict__ W2, const float* __restrict__ W3,
    float* __restrict__ out)
{
    __shared__ unsigned short buf[NROW];            // 64 KiB bf16
    const int t = threadIdx.x;
    const int w = t >> 6, c = t & 15, g = (t >> 4) & 3;
    const float* __restrict__ xrow = x + (size_t)blockIdx.x * NROW;
    float* __restrict__ orow = out + (size_t)blockIdx.x * NROW;
    const f32x4 vzero = {0.f, 0.f, 0.f, 0.f};

    // stage-A weights (W3), hoisted to overlap staging-load latency
    bf16x8 wA[2];
    wA[0] = wfrag(W3, 0, c, g);
    wA[1] = wfrag(W3, 1, c, g);

    // ---- stage x: fp32 global -> bf16 LDS [mA=(p,q)][r], swizzled ----
#pragma unroll
    for (int v = 0; v < 8; ++v) {
        float4 f = ((const float4*)xrow)[v * 1024 + t];   // coalesced
        int mA = 128 * v + (t >> 3);
        int r0 = 4 * (t & 7);
        unsigned lo = (unsigned)f2b(f.x) | ((unsigned)f2b(f.y) << 16);
        unsigned hi = (unsigned)f2b(f.z) | ((unsigned)f2b(f.w) << 16);
        *(uint2*)(buf + swz(mA, r0)) = make_uint2(lo, hi);
    }
    __syncthreads();                                  // B1: x staged

    // ---- stage A: contract r.  yA[(p,k'),q] = sum_r x[(p,q),r] W3[r,k'] ----
    bf16x8 fa[4];
#pragma unroll
    for (int mt = 0; mt < 4; ++mt)
        fa[mt] = ldsfrag(buf, 64 * w + 16 * mt + c, g);  // A: row mA, k=r
    __syncthreads();                                  // B2: x reads done

#pragma unroll
    for (int nt = 0; nt < 2; ++nt) {
        const int kp = 16 * nt + c;                   // n-dim: k'
#pragma unroll
        for (int mt = 0; mt < 4; ++mt) {
            f32x4 a = __builtin_amdgcn_mfma_f32_16x16x32_bf16(fa[mt], wA[nt], vzero, 0, 0, 0);
            const int p  = 2 * w + (mt >> 1);
            const int q0 = 16 * (mt & 1) + 4 * g;     // rows q0..q0+3 per reg
            unsigned lo = (unsigned)f2b(a[0]) | ((unsigned)f2b(a[1]) << 16);
            unsigned hi = (unsigned)f2b(a[2]) | ((unsigned)f2b(a[3]) << 16);
            *(uint2*)(buf + swz(p * 32 + kp, q0)) = make_uint2(lo, hi);  // b64
        }
    }
    __syncthreads();                                  // B3: yA written

    // ---- stage B: contract q.  yB[(j,k),p] = sum_q yA[(p,k),q] W2[q,j] ----
    bf16x8 wB[2];
    wB[0] = wfrag(W2, 0, c, g);                       // A-operand: rows j, k=q
    wB[1] = wfrag(W2, 1, c, g);
    bf16x8 fb[4];
#pragma unroll
    for (int mt = 0; mt < 4; ++mt)
        fb[mt] = ldsfrag(buf, 64 * w + 16 * mt + c, g);  // B-operand: col mB, k=q
    __syncthreads();                                  // B4: yA reads done

#pragma unroll
    for (int jt = 0; jt < 2; ++jt) {
#pragma unroll
        for (int mt = 0; mt < 4; ++mt) {
            f32x4 a = __builtin_amdgcn_mfma_f32_16x16x32_bf16(wB[jt], fb[mt], vzero, 0, 0, 0);
            const int k = 16 * (mt & 1) + c;          // from mB col
            const int p = 2 * w + (mt >> 1);
#pragma unroll
            for (int rg = 0; rg < 4; ++rg) {
                const int j = 16 * jt + 4 * g + rg;   // D row
                buf[swz(j * 32 + k, p)] = f2b(a[rg]); // scalar b16, ~8-way banks
            }
        }
    }
    __syncthreads();                                  // B5: yB written

    // ---- stage C: contract p.  out[i,j,k] = sum_p yB[(j,k),p] W1[p,i] ----
    bf16x8 wC[2];
    wC[0] = wfrag(W1, 0, c, g);
    wC[1] = wfrag(W1, 1, c, g);
    bf16x8 fc[4];
#pragma unroll
    for (int mt = 0; mt < 4; ++mt)
        fc[mt] = ldsfrag(buf, 64 * w + 16 * mt + c, g);  // A: row mC, k=p
    // no further LDS writes -> no barrier needed

#pragma unroll
    for (int nt = 0; nt < 2; ++nt) {
        const int i = 16 * nt + c;                    // n-dim
#pragma unroll
        for (int mt = 0; mt < 4; ++mt) {
            f32x4 a = __builtin_amdgcn_mfma_f32_16x16x32_bf16(fc[mt], wC[nt], vzero, 0, 0, 0);
            const int j  = 2 * w + (mt >> 1);
            const int k0 = 16 * (mt & 1) + 4 * g;     // regs = k0..k0+3
            *(float4*)(orow + i * 1024 + j * 32 + k0) =
                make_float4(a[0], a[1], a[2], a[3]);  // coalesced 64B/line
        }
    }
}

extern "C" void kernel_launch(void* const* d_in, const int* in_sizes, int n_in,
                              void* d_out, int out_size, void* d_ws, size_t ws_size,
                              hipStream_t stream) {
    const float* x  = (const float*)d_in[0];
    const float* W1 = (const float*)d_in[1];
    const float* W2 = (const float*)d_in[2];
    const float* W3 = (const float*)d_in[3];
    float* outp = (float*)d_out;

    const int batch = in_sizes[0] / NROW;             // 2048
    kron3_mfma<<<dim3(batch), dim3(1024), 0, stream>>>(x, W1, W2, W3, outp);
}